// Round 1
// baseline (31876.288 us; speedup 1.0000x reference)
//
#include <hip/hip_runtime.h>
#include <stdint.h>

// RevGRU encoder, MI355X.
// R7: 2-HOP scan. R6 had 4 cross-WG rendezvous/step (h2, r1, h1, r2 gathers) at the
// ~4.8us/hop floor -> 19.2us/step of pure latency. Restructure:
//   - every scan WG keeps FULL h1/h2 replicated in LDS and performs the full
//     elementwise h-update itself (bit-deterministic across WGs: f32 partials
//     summed in fixed order) -> h-gather hops eliminated.
//   - g-matmul is K-PARTITIONED: WG cg<4 ("R-WG") owns r-cols [cg*64,+64) and
//     computes a 64-K partial GEMM over ALL 256 g-cols; WGs cg>=4 ("Q-WG") own
//     64 q-cols each. Exchange per half-step = q (16x256) + 4 f32 partial slabs
//     (4 x 16x256). Two hops/step total.
//   - XCD colocation: the 8 WGs of a (layer,domain) group share bid%8.
//   - L1 X1 ring reads: batched 20-wide tagged prefetch for t+1 at end of step.
// Producers / prep / gemmx unchanged from R6.

typedef __attribute__((ext_vector_type(8))) short short8;
typedef __attribute__((ext_vector_type(4))) float floatx4;

#define MFMA16(a,b,c) __builtin_amdgcn_mfma_f32_16x16x32_bf16((a),(b),(c),0,0,0)

__device__ __forceinline__ short bf16_rne(float f) {
  uint32_t u = __float_as_uint(f);
  u += 0x7FFFu + ((u >> 16) & 1u);
  return (short)(u >> 16);
}
__device__ __forceinline__ float bf16f(short s) {
  return __uint_as_float(((uint32_t)(uint16_t)s) << 16);
}
__device__ __forceinline__ void st64(unsigned long long* p, unsigned long long v) {
  __hip_atomic_store(p, v, __ATOMIC_RELAXED, __HIP_MEMORY_SCOPE_AGENT);
}
__device__ __forceinline__ unsigned long long ld64(const unsigned long long* p) {
  return __hip_atomic_load(p, __ATOMIC_RELAXED, __HIP_MEMORY_SCOPE_AGENT);
}

#define SCALE_F 8388608.0f
#define INV_S   (1.0f/8388608.0f)

// ---- static device scratch ----
__device__ float g_X[50331648];            // X0: 32768 x 1536 (layer-0 x-projections)
__device__ short g_WTh[2][786432];         // per-layer x-proj weights, transposed, split hi
__device__ short g_WTl[2][786432];         // split lo
__device__ float g_biasL[2][1536];
__device__ unsigned long long g_ch[2][4][6][4096];  // only [1][dm][5][0] used: L1 progress
__device__ unsigned long long g_h0s[16777216];      // [t][row][col] tagged {tag, f32 h0f}
__device__ unsigned long long g_x1r[3145728];       // ring [t&31][row][1536] tagged {tag, f32}
__device__ unsigned long long g_q1[2][4][4096];     // q1 channel [L][dm][row*256+col]
__device__ unsigned long long g_q2[2][4][4096];
__device__ unsigned long long g_p1[2][4][4][4096];  // g1 partials [L][dm][rwg][row*256+col]
__device__ unsigned long long g_p2[2][4][4][4096];
__device__ unsigned g_epoch;

__global__ void bump_epoch() { g_epoch = g_epoch + 1u; }

// ------------------------------------------------------------------
__global__ void prep_x(const float* __restrict__ Wz1, const float* __restrict__ bz1,
                       const float* __restrict__ Wg1, const float* __restrict__ bg1,
                       const float* __restrict__ Wz2, const float* __restrict__ bz2,
                       const float* __restrict__ Wg2, const float* __restrict__ bg2,
                       int layer, int* __restrict__ d_out, int zero_extra) {
  int idx = blockIdx.x * 256 + threadIdx.x;   // grid covers 512*1536 exactly
  int k = idx / 1536;
  int c = idx - k * 1536;
  const float* W; const float* bb; int cc; int ncols;
  if (c < 512)       { W = Wz1; bb = bz1; cc = c;        ncols = 512; }
  else if (c < 768)  { W = Wg1; bb = bg1; cc = c - 512;  ncols = 256; }
  else if (c < 1280) { W = Wz2; bb = bz2; cc = c - 768;  ncols = 512; }
  else               { W = Wg2; bb = bg2; cc = c - 1280; ncols = 256; }
  float wv = W[(size_t)layer * 768 * ncols + (size_t)k * ncols + cc];
  short hi = bf16_rne(wv);
  short lo = bf16_rne(wv - bf16f(hi));
  g_WTh[layer][(size_t)c * 512 + k] = hi;
  g_WTl[layer][(size_t)c * 512 + k] = lo;
  if (k == 0) g_biasL[layer][c] = bb[layer * ncols + cc];
  if (zero_extra && idx < 6400) d_out[65536 + idx] = 0;   // saved[0] = h0 = zeros
}

// ------------------------------------------------------------------
__global__ __launch_bounds__(256)
void gemmx_kernel(const int* __restrict__ seq, const float* __restrict__ emb) {
  __shared__ float At[128][36];
  __shared__ short Bhi[128][40];
  __shared__ short Blo[128][40];
  __shared__ int toks[128];
  int tid = threadIdx.x;
  int r0 = blockIdx.x * 128;
  int c0 = blockIdx.y * 128;
  if (tid < 128) toks[tid] = seq[r0 + tid];
  int lane = tid & 63;
  int wid = tid >> 6;
  int wm = wid & 1, wn = wid >> 1;
  int lm = lane & 15, lq = lane >> 4;
  floatx4 zero4 = {0.f, 0.f, 0.f, 0.f};
  floatx4 acc[4][4];
#pragma unroll
  for (int a = 0; a < 4; ++a)
#pragma unroll
    for (int b = 0; b < 4; ++b) acc[a][b] = zero4;
  __syncthreads();
  int am = tid >> 1;
  int ah = (tid & 1) * 16;
  const float* arow = emb + (size_t)toks[am] * 512;
  const short* bh_base = g_WTh[0] + (size_t)(c0 + am) * 512;
  const short* bl_base = g_WTl[0] + (size_t)(c0 + am) * 512;
  for (int kb = 0; kb < 16; ++kb) {
    int k0 = kb * 32 + ah;
    float4 a0 = *(const float4*)(arow + k0);
    float4 a1 = *(const float4*)(arow + k0 + 4);
    float4 a2 = *(const float4*)(arow + k0 + 8);
    float4 a3 = *(const float4*)(arow + k0 + 12);
    short4 b0 = *(const short4*)(bh_base + k0);
    short4 b1 = *(const short4*)(bh_base + k0 + 4);
    short4 b2 = *(const short4*)(bh_base + k0 + 8);
    short4 b3 = *(const short4*)(bh_base + k0 + 12);
    short4 l0 = *(const short4*)(bl_base + k0);
    short4 l1 = *(const short4*)(bl_base + k0 + 4);
    short4 l2 = *(const short4*)(bl_base + k0 + 8);
    short4 l3 = *(const short4*)(bl_base + k0 + 12);
    __syncthreads();
    *(float4*)&At[am][ah]      = a0;
    *(float4*)&At[am][ah + 4]  = a1;
    *(float4*)&At[am][ah + 8]  = a2;
    *(float4*)&At[am][ah + 12] = a3;
    *(short4*)&Bhi[am][ah]      = b0;
    *(short4*)&Bhi[am][ah + 4]  = b1;
    *(short4*)&Bhi[am][ah + 8]  = b2;
    *(short4*)&Bhi[am][ah + 12] = b3;
    *(short4*)&Blo[am][ah]      = l0;
    *(short4*)&Blo[am][ah + 4]  = l1;
    *(short4*)&Blo[am][ah + 8]  = l2;
    *(short4*)&Blo[am][ah + 12] = l3;
    __syncthreads();
    short8 afh[4], afl[4];
#pragma unroll
    for (int mt = 0; mt < 4; ++mt) {
      const float* ap = &At[wm*64 + mt*16 + lm][lq*8];
#pragma unroll
      for (int j = 0; j < 8; ++j) {
        float v = ap[j];
        short hi = bf16_rne(v);
        afh[mt][j] = hi;
        afl[mt][j] = bf16_rne(v - bf16f(hi));
      }
    }
#pragma unroll
    for (int nt = 0; nt < 4; ++nt) {
      short8 bfh = *(short8*)&Bhi[wn*64 + nt*16 + lm][lq*8];
      short8 bfl = *(short8*)&Blo[wn*64 + nt*16 + lm][lq*8];
#pragma unroll
      for (int mt = 0; mt < 4; ++mt) {
        acc[mt][nt] = MFMA16(afh[mt], bfh, acc[mt][nt]);
        acc[mt][nt] = MFMA16(afl[mt], bfh, acc[mt][nt]);
        acc[mt][nt] = MFMA16(afh[mt], bfl, acc[mt][nt]);
      }
    }
  }
#pragma unroll
  for (int nt = 0; nt < 4; ++nt) {
    int gc = c0 + wn*64 + nt*16 + lm;
    float bv = g_biasL[0][gc];
#pragma unroll
    for (int mt = 0; mt < 4; ++mt) {
#pragma unroll
      for (int i = 0; i < 4; ++i) {
        int gr = r0 + wm*64 + mt*16 + lq*4 + i;
        g_X[(size_t)gr * 1536 + gc] = acc[mt][nt][i] + bv;
      }
    }
  }
}

// ------------------------------------------------------------------
// Gather q + 4 partial slabs for this thread's 8 h-columns, then do the
// replicated h-update. Deterministic across WGs (fixed f32 sum order).
#define GUPDATE(QCH, PCH, XG, HARR, HOFF, DOSAVED)                                 \
  {                                                                                \
    _Pragma("unroll")                                                              \
    for (int hch = 0; hch < 2; ++hch) {                                            \
      int cb = ug * 8 + hch * 4;                                                   \
      const unsigned long long* qb = &QCH[Lx][dm][xr * 256 + cb];                  \
      const unsigned long long* pb = &PCH[Lx][dm][0][xr * 256 + cb];               \
      unsigned long long pv[20];                                                   \
      _Pragma("unroll")                                                            \
      for (int cc = 0; cc < 4; ++cc) {                                             \
        _Pragma("unroll")                                                          \
        for (int g = 0; g < 4; ++g) pv[cc * 5 + g] = ld64(pb + g * 4096 + cc);     \
        pv[cc * 5 + 4] = ld64(qb + cc);                                            \
      }                                                                            \
      unsigned pend = 0;                                                           \
      _Pragma("unroll")                                                            \
      for (int i2 = 0; i2 < 20; ++i2)                                              \
        if ((unsigned)(pv[i2] >> 32) != tagp) pend |= 1u << i2;                    \
      while (pend) {                                                               \
        __builtin_amdgcn_s_sleep(1);                                               \
        _Pragma("unroll")                                                          \
        for (int i2 = 0; i2 < 20; ++i2)                                            \
          if (pend & (1u << i2)) {                                                 \
            int cc2 = i2 / 5, g2 = i2 - cc2 * 5;                                   \
            unsigned long long vv = (g2 == 4) ? ld64(qb + cc2)                     \
                                              : ld64(pb + g2 * 4096 + cc2);       \
            if ((unsigned)(vv >> 32) == tagp) { pv[i2] = vv; pend &= ~(1u << i2); }\
          }                                                                        \
      }                                                                            \
      _Pragma("unroll")                                                            \
      for (int cc = 0; cc < 4; ++cc) {                                             \
        int c = cb + cc;                                                           \
        float gs = __uint_as_float((unsigned)pv[cc * 5 + 0]);                      \
        gs += __uint_as_float((unsigned)pv[cc * 5 + 1]);                           \
        gs += __uint_as_float((unsigned)pv[cc * 5 + 2]);                           \
        gs += __uint_as_float((unsigned)pv[cc * 5 + 3]);                           \
        float gv = tanhf(gs + (XG)[hch * 4 + cc]);                                 \
        int q = (int)(unsigned)pv[cc * 5 + 4];                                     \
        int hold = HARR[xr][c];                                                    \
        float zf = (float)q * (1.0f / 1024.0f);                                    \
        int ni = (int)rintf((1.0f - zf) * gv * SCALE_F);                           \
        int hnew = (hold >> 10) * q + (((hold & 1023) * q) >> 10) + ni;            \
        if (t >= lens[xr]) hnew = hold;                                            \
        HARR[xr][c] = hnew;                                                        \
        float hv = (float)hnew;                                                    \
        short sa0 = bf16_rne(hv); float sr1 = hv - bf16f(sa0);                     \
        short sa1 = bf16_rne(sr1);                                                 \
        phi[xr][c] = sa0; pmi[xr][c] = sa1; plo[xr][c] = bf16_rne(sr1 - bf16f(sa1));\
        if (own) {                                                                 \
          if (Lx == 0)                                                             \
            st64(&g_h0s[((size_t)(t * 64) + rb0 + xr) * 512 + (HOFF) + c],         \
                 ((unsigned long long)tagp << 32) | __float_as_uint(hv * INV_S));  \
          else if ((DOSAVED) && c < 100)                                           \
            d_out[65536 + (t + 1) * 6400 + (rb0 + xr) * 100 + c] = hnew;           \
          if (t == 511)                                                            \
            d_out[Lx * 32768 + (rb0 + xr) * 512 + (HOFF) + c] = hnew;              \
        }                                                                          \
      }                                                                            \
    }                                                                              \
  }

__global__ __launch_bounds__(512, 1)
void fused_kernel(const float* __restrict__ Wz1g, const float* __restrict__ Wg1g,
                  const float* __restrict__ Wz2g, const float* __restrict__ Wg2g,
                  const int* __restrict__ lengths, int* __restrict__ d_out) {
  __shared__ int   h1i[16][264];
  __shared__ int   h2i[16][264];
  __shared__ short phi[16][264];
  __shared__ short pmi[16][264];
  __shared__ short plo[16][264];
  __shared__ float redbuf[2304];
  __shared__ short pg0[16][72];
  __shared__ short pg1[16][72];
  __shared__ int lens[16];
  __shared__ short ahs[16][520];
  __shared__ short als[16][520];

  int tid = threadIdx.x;
  int bid = blockIdx.x;
  int lane = tid & 63, wv = tid >> 6;   // 8 waves
  int lm = lane & 15, lq = lane >> 4;
  unsigned ep = g_epoch;

  if (bid >= 64) {
    // ================== role: X1 producer (48 WGs) — unchanged ==================
    int xw = bid - 64;
    int r4 = xw & 3;        // row tile (16 rows)
    int cs = xw >> 2;       // col slice (128 cols), 0..11
    int colx = cs * 128 + wv * 16 + lm;
    short8 bh[16], bl[16];
#pragma unroll
    for (int kf = 0; kf < 16; ++kf) {
      bh[kf] = *(const short8*)&g_WTh[1][(size_t)colx * 512 + kf * 32 + lq * 8];
      bl[kf] = *(const short8*)&g_WTl[1][(size_t)colx * 512 + kf * 32 + lq * 8];
    }
    float bvx = g_biasL[1][colx];
    int sr2 = tid >> 5;
    int cb  = (tid & 31) * 16;

    for (int t = 0; t < 512; ++t) {
      unsigned tagt = (ep << 10) | (unsigned)(t + 1);
      {
        const unsigned long long* hp = &g_h0s[((size_t)(t * 64) + r4 * 16 + sr2) * 512 + cb];
        unsigned long long v[16];
        do { v[0] = ld64(hp); } while ((unsigned)(v[0] >> 32) != tagt);
#pragma unroll
        for (int i = 1; i < 16; ++i) v[i] = ld64(hp + i);
        unsigned pend = 0;
#pragma unroll
        for (int i = 1; i < 16; ++i)
          if ((unsigned)(v[i] >> 32) != tagt) pend |= 1u << i;
        while (pend) {
          __builtin_amdgcn_s_sleep(1);
#pragma unroll
          for (int i = 1; i < 16; ++i)
            if (pend & (1u << i)) {
              v[i] = ld64(hp + i);
              if ((unsigned)(v[i] >> 32) == tagt) pend &= ~(1u << i);
            }
        }
#pragma unroll
        for (int i = 0; i < 16; ++i) {
          float f = __uint_as_float((unsigned)v[i]);
          short hi = bf16_rne(f);
          ahs[sr2][cb + i] = hi;
          als[sr2][cb + i] = bf16_rne(f - bf16f(hi));
        }
      }
      __syncthreads();
      floatx4 acc = {0.f, 0.f, 0.f, 0.f};
#pragma unroll
      for (int kf = 0; kf < 16; ++kf) {
        short8 a0 = *(short8*)&ahs[lm][kf * 32 + lq * 8];
        short8 a1 = *(short8*)&als[lm][kf * 32 + lq * 8];
        acc = MFMA16(a0, bh[kf], acc);
        acc = MFMA16(a1, bh[kf], acc);
        acc = MFMA16(a0, bl[kf], acc);
      }
      if (t >= 25) {
        if (tid < 4) {
          unsigned need = (ep << 10) | (unsigned)(t - 24);
          while ((unsigned)(ld64(&g_ch[1][tid][5][0]) >> 32) < need) __builtin_amdgcn_s_sleep(2);
        }
      }
      __syncthreads();
#pragma unroll
      for (int i = 0; i < 4; ++i) {
        int row = r4 * 16 + lq * 4 + i;
        st64(&g_x1r[((size_t)(t & 31) * 64 + row) * 1536 + colx],
             ((unsigned long long)tagt << 32) | __float_as_uint(acc[i] + bvx));
      }
      __syncthreads();
    }
    return;
  }

  // ================== role: scan, 2-hop structure ==================
  // bid mapping: grp = bid&7 (shared XCD for the 8 cooperating WGs), cg = bid>>3.
  int grp = bid & 7;
  int cg  = bid >> 3;          // 0..3: R-WG (owns 64 r-cols / 64-K g slice); 4..7: Q-WG
  int Lx  = grp >> 2;
  int dm  = grp & 3;
  int rb0 = dm * 16;
  int isR = (cg < 4);

  if (tid < 16) lens[tid] = lengths[rb0 + tid];
  for (int i = tid; i < 16 * 264; i += 512) {
    ((int*)h1i)[i] = 0; ((int*)h2i)[i] = 0;
    ((short*)phi)[i] = 0; ((short*)pmi)[i] = 0; ((short*)plo)[i] = 0;
  }

  // ---- preload weights into registers ----
  short8 wz1a[4], wz1b[4], wz1c[4], wz2a[4], wz2b[4], wz2c[4];
  short8 wgp1a[2][2], wgp1b[2][2], wgp2a[2][2], wgp2b[2][2];  // [coltile s][kstep]
  {
    int nt = wv & 3, kh = wv >> 2;
    int czl = nt * 16 + lm;                                  // local z-col 0..63
    int colz = isR ? (256 + cg * 64 + czl) : ((cg - 4) * 64 + czl);
    const float* W1 = Wz1g + (size_t)Lx * 768 * 512 + (size_t)512 * 512 + colz;
    const float* W2 = Wz2g + (size_t)Lx * 768 * 512 + (size_t)512 * 512 + colz;
#pragma unroll
    for (int ks = 0; ks < 4; ++ks) {
      int k0 = kh * 128 + ks * 32 + lq * 8;
      short8 t0, t1, t2, u0, u1, u2;
#pragma unroll
      for (int j = 0; j < 8; ++j) {
        float v = W1[(size_t)(k0 + j) * 512] * INV_S;   // pre-scale: A is raw int h
        short a0 = bf16_rne(v); float r1 = v - bf16f(a0);
        short a1 = bf16_rne(r1); float r2 = r1 - bf16f(a1);
        t0[j] = a0; t1[j] = a1; t2[j] = bf16_rne(r2);
        float v2 = W2[(size_t)(k0 + j) * 512] * INV_S;
        short d0 = bf16_rne(v2); float s1 = v2 - bf16f(d0);
        short d1 = bf16_rne(s1); float s2 = s1 - bf16f(d1);
        u0[j] = d0; u1[j] = d1; u2[j] = bf16_rne(s2);
      }
      wz1a[ks] = t0; wz1b[ks] = t1; wz1c[ks] = t2;
      wz2a[ks] = u0; wz2b[ks] = u1; wz2c[ks] = u2;
    }
    if (isR) {
      // g-weights: rows (k) = cg*64 .. +64 of the recurrent block, ALL 256 cols.
#pragma unroll
      for (int s = 0; s < 2; ++s) {
        int colg = (2 * wv + s) * 16 + lm;
        const float* G1 = Wg1g + (size_t)Lx * 768 * 256 + (size_t)(512 + cg * 64) * 256 + colg;
        const float* G2 = Wg2g + (size_t)Lx * 768 * 256 + (size_t)(512 + cg * 64) * 256 + colg;
#pragma unroll
        for (int ks = 0; ks < 2; ++ks) {
          short8 t0, t1, u0, u1;
#pragma unroll
          for (int j = 0; j < 8; ++j) {
            float v = G1[(size_t)(ks * 32 + lq * 8 + j) * 256];
            short a0 = bf16_rne(v);
            t0[j] = a0; t1[j] = bf16_rne(v - bf16f(a0));
            float v2 = G2[(size_t)(ks * 32 + lq * 8 + j) * 256];
            short d0 = bf16_rne(v2);
            u0[j] = d0; u1[j] = bf16_rne(v2 - bf16f(d0));
          }
          wgp1a[s][ks] = t0; wgp1b[s][ks] = t1; wgp2a[s][ks] = u0; wgp2b[s][ks] = u1;
        }
      }
    }
  }
  __syncthreads();

  int xr = tid & 15;             // batch row
  int xc = tid >> 4;             // 0..31: z-col pair index / h-col group
  int ug = xc;
  int own = ((ug >> 2) == cg);   // this WG owns h-cols [cg*32, +32) for global writes
  int zoff = isR ? (256 + cg * 64 + 2 * xc) : ((cg - 4) * 64 + 2 * xc);

  float xz1a, xz1b, xz2a, xz2b, xg1[8], xg2[8];

  auto ldx = [&](int tt) {       // L0: plain cached loads from precomputed X0
    const float* base = g_X + (size_t)(tt * 64 + rb0 + xr) * 1536;
    float2 a = *(const float2*)(base + zoff);
    xz1a = a.x; xz1b = a.y;
    float4 b0 = *(const float4*)(base + 512 + ug * 8);
    float4 b1 = *(const float4*)(base + 516 + ug * 8);
    xg1[0] = b0.x; xg1[1] = b0.y; xg1[2] = b0.z; xg1[3] = b0.w;
    xg1[4] = b1.x; xg1[5] = b1.y; xg1[6] = b1.z; xg1[7] = b1.w;
    float2 c = *(const float2*)(base + 768 + zoff);
    xz2a = c.x; xz2b = c.y;
    float4 d0 = *(const float4*)(base + 1280 + ug * 8);
    float4 d1 = *(const float4*)(base + 1284 + ug * 8);
    xg2[0] = d0.x; xg2[1] = d0.y; xg2[2] = d0.z; xg2[3] = d0.w;
    xg2[4] = d1.x; xg2[5] = d1.y; xg2[6] = d1.z; xg2[7] = d1.w;
  };
  auto pfx1 = [&](int tt) {      // L1: batched tagged prefetch from X1 ring
    unsigned tg = (ep << 10) | (unsigned)(tt + 1);
    const unsigned long long* base = &g_x1r[((size_t)((tt & 31) * 64) + rb0 + xr) * 1536];
    const unsigned long long* ap[20];
    ap[0] = base + zoff; ap[1] = base + zoff + 1;
#pragma unroll
    for (int j = 0; j < 8; ++j) ap[2 + j] = base + 512 + ug * 8 + j;
    ap[10] = base + 768 + zoff; ap[11] = base + 768 + zoff + 1;
#pragma unroll
    for (int j = 0; j < 8; ++j) ap[12 + j] = base + 1280 + ug * 8 + j;
    unsigned long long v[20];
#pragma unroll
    for (int i = 0; i < 20; ++i) v[i] = ld64(ap[i]);
    unsigned pend = 0;
#pragma unroll
    for (int i = 0; i < 20; ++i)
      if ((unsigned)(v[i] >> 32) != tg) pend |= 1u << i;
    while (pend) {
      __builtin_amdgcn_s_sleep(1);
#pragma unroll
      for (int i = 0; i < 20; ++i)
        if (pend & (1u << i)) {
          unsigned long long vv = ld64(ap[i]);
          if ((unsigned)(vv >> 32) == tg) { v[i] = vv; pend &= ~(1u << i); }
        }
    }
    xz1a = __uint_as_float((unsigned)v[0]);
    xz1b = __uint_as_float((unsigned)v[1]);
#pragma unroll
    for (int j = 0; j < 8; ++j) xg1[j] = __uint_as_float((unsigned)v[2 + j]);
    xz2a = __uint_as_float((unsigned)v[10]);
    xz2b = __uint_as_float((unsigned)v[11]);
#pragma unroll
    for (int j = 0; j < 8; ++j) xg2[j] = __uint_as_float((unsigned)v[12 + j]);
  };

  if (Lx == 0) ldx(0); else pfx1(0);

  for (int t = 0; t < 512; ++t) {
    unsigned tagp = (ep << 10) | (unsigned)(t + 1);

    // ---------- Phase A: z1 (own 64 cols) ----------
    {
      int nt = wv & 3, kh = wv >> 2;
      floatx4 acc = {0.f, 0.f, 0.f, 0.f};
#pragma unroll
      for (int ks = 0; ks < 4; ++ks) {
        int k0 = kh * 128 + ks * 32 + lq * 8;
        short8 a0 = *(short8*)&phi[lm][k0];
        short8 a1 = *(short8*)&pmi[lm][k0];
        short8 a2 = *(short8*)&plo[lm][k0];
        acc = MFMA16(a0, wz1a[ks], acc);
        acc = MFMA16(a0, wz1b[ks], acc);
        acc = MFMA16(a1, wz1a[ks], acc);
        acc = MFMA16(a1, wz1b[ks], acc);
        acc = MFMA16(a0, wz1c[ks], acc);
        acc = MFMA16(a2, wz1a[ks], acc);
      }
#pragma unroll
      for (int i = 0; i < 4; ++i) redbuf[kh * 1088 + (lq * 4 + i) * 68 + nt * 16 + lm] = acc[i];
    }
    __syncthreads();   // (1)
    {
#pragma unroll
      for (int u = 0; u < 2; ++u) {
        int cc = 2 * xc + u;
        float pre = redbuf[xr * 68 + cc] + redbuf[1088 + xr * 68 + cc] + (u ? xz1b : xz1a);
        float s = 1.0f / (1.0f + expf(-pre));
        if (isR) {
          float p = s * ((float)h2i[xr][cg * 64 + cc] * INV_S);
          short p0 = bf16_rne(p);
          pg0[xr][cc] = p0;
          pg1[xr][cc] = bf16_rne(p - bf16f(p0));
        } else {
          float qf = floorf((0.875f * s + 0.125f) * 1024.0f);
          int qi = (int)qf; qi = qi < 1 ? 1 : (qi > 1024 ? 1024 : qi);
          st64(&g_q1[Lx][dm][xr * 256 + (cg - 4) * 64 + cc],
               ((unsigned long long)tagp << 32) | (unsigned)qi);
        }
      }
    }
    __syncthreads();   // (2)
    if (isR) {         // g1 partial over local 64-K slice, all 256 cols
#pragma unroll
      for (int s = 0; s < 2; ++s) {
        floatx4 acc = {0.f, 0.f, 0.f, 0.f};
#pragma unroll
        for (int ks = 0; ks < 2; ++ks) {
          short8 a0 = *(short8*)&pg0[lm][ks * 32 + lq * 8];
          short8 a1 = *(short8*)&pg1[lm][ks * 32 + lq * 8];
          acc = MFMA16(a0, wgp1a[s][ks], acc);
          acc = MFMA16(a1, wgp1a[s][ks], acc);
          acc = MFMA16(a0, wgp1b[s][ks], acc);
        }
        int col = (2 * wv + s) * 16 + lm;
#pragma unroll
        for (int i = 0; i < 4; ++i)
          st64(&g_p1[Lx][dm][cg][(size_t)(lq * 4 + i) * 256 + col],
               ((unsigned long long)tagp << 32) | __float_as_uint(acc[i]));
      }
    }

    // ---------- Phase B: hop-alpha gather -> replicated h1 update -> z2 ----------
    GUPDATE(g_q1, g_p1, xg1, h1i, 0, (Lx == 1));
    __syncthreads();   // (3) h1 splits visible
    {
      int nt = wv & 3, kh = wv >> 2;
      floatx4 acc = {0.f, 0.f, 0.f, 0.f};
#pragma unroll
      for (int ks = 0; ks < 4; ++ks) {
        int k0 = kh * 128 + ks * 32 + lq * 8;
        short8 a0 = *(short8*)&phi[lm][k0];
        short8 a1 = *(short8*)&pmi[lm][k0];
        short8 a2 = *(short8*)&plo[lm][k0];
        acc = MFMA16(a0, wz2a[ks], acc);
        acc = MFMA16(a0, wz2b[ks], acc);
        acc = MFMA16(a1, wz2a[ks], acc);
        acc = MFMA16(a1, wz2b[ks], acc);
        acc = MFMA16(a0, wz2c[ks], acc);
        acc = MFMA16(a2, wz2a[ks], acc);
      }
#pragma unroll
      for (int i = 0; i < 4; ++i) redbuf[kh * 1088 + (lq * 4 + i) * 68 + nt * 16 + lm] = acc[i];
    }
    __syncthreads();   // (4)
    {
#pragma unroll
      for (int u = 0; u < 2; ++u) {
        int cc = 2 * xc + u;
        float pre = redbuf[xr * 68 + cc] + redbuf[1088 + xr * 68 + cc] + (u ? xz2b : xz2a);
        float s = 1.0f / (1.0f + expf(-pre));
        if (isR) {
          float p = s * ((float)h1i[xr][cg * 64 + cc] * INV_S);
          short p0 = bf16_rne(p);
          pg0[xr][cc] = p0;
          pg1[xr][cc] = bf16_rne(p - bf16f(p0));
        } else {
          float qf = floorf((0.875f * s + 0.125f) * 1024.0f);
          int qi = (int)qf; qi = qi < 1 ? 1 : (qi > 1024 ? 1024 : qi);
          st64(&g_q2[Lx][dm][xr * 256 + (cg - 4) * 64 + cc],
               ((unsigned long long)tagp << 32) | (unsigned)qi);
        }
      }
    }
    __syncthreads();   // (5)
    if (isR) {
#pragma unroll
      for (int s = 0; s < 2; ++s) {
        floatx4 acc = {0.f, 0.f, 0.f, 0.f};
#pragma unroll
        for (int ks = 0; ks < 2; ++ks) {
          short8 a0 = *(short8*)&pg0[lm][ks * 32 + lq * 8];
          short8 a1 = *(short8*)&pg1[lm][ks * 32 + lq * 8];
          acc = MFMA16(a0, wgp2a[s][ks], acc);
          acc = MFMA16(a1, wgp2a[s][ks], acc);
          acc = MFMA16(a0, wgp2b[s][ks], acc);
        }
        int col = (2 * wv + s) * 16 + lm;
#pragma unroll
        for (int i = 0; i < 4; ++i)
          st64(&g_p2[Lx][dm][cg][(size_t)(lq * 4 + i) * 256 + col],
               ((unsigned long long)tagp << 32) | __float_as_uint(acc[i]));
      }
    }

    // ---------- Phase C: hop-beta gather -> replicated h2 update ----------
    GUPDATE(g_q2, g_p2, xg2, h2i, 256, 0);

    // prefetch next step's x-parts (register-only)
    if (t < 511) { if (Lx == 0) ldx(t + 1); else pfx1(t + 1); }
    __syncthreads();   // (6) h2 splits + prefetch complete
    if (Lx == 1 && cg == 0 && tid == 0)
      st64(&g_ch[1][dm][5][0], ((unsigned long long)tagp << 32) | 1u);
  }
}

// ------------------------------------------------------------------
extern "C" void kernel_launch(void* const* d_in, const int* in_sizes, int n_in,
                              void* d_out, int out_size, void* d_ws, size_t ws_size,
                              hipStream_t stream) {
  const int*   seq     = (const int*)d_in[0];
  const int*   lengths = (const int*)d_in[1];
  const float* emb     = (const float*)d_in[2];
  const float* Wz1     = (const float*)d_in[3];
  const float* bz1     = (const float*)d_in[4];
  const float* Wg1     = (const float*)d_in[5];
  const float* bg1     = (const float*)d_in[6];
  const float* Wz2     = (const float*)d_in[7];
  const float* bz2     = (const float*)d_in[8];
  const float* Wg2     = (const float*)d_in[9];
  const float* bg2     = (const float*)d_in[10];
  int* out = (int*)d_out;
  (void)in_sizes; (void)n_in; (void)out_size; (void)d_ws; (void)ws_size;

  bump_epoch<<<1, 1, 0, stream>>>();
  prep_x<<<3072, 256, 0, stream>>>(Wz1, bz1, Wg1, bg1, Wz2, bz2, Wg2, bg2, 0, out, 1);
  prep_x<<<3072, 256, 0, stream>>>(Wz1, bz1, Wg1, bg1, Wz2, bz2, Wg2, bg2, 1, out, 0);
  gemmx_kernel<<<dim3(256, 12), 256, 0, stream>>>(seq, emb);
  fused_kernel<<<112, 512, 0, stream>>>(Wz1, Wg1, Wz2, Wg2, lengths, out);
}

// Round 2
// 8738.188 us; speedup vs baseline: 3.6479x; 3.6479x over previous
//
#include <hip/hip_runtime.h>
#include <stdint.h>

// RevGRU encoder, MI355X.
// R8: revert to R6's 4-hop column-partitioned scan (12.25ms known-good; R7's
// replicated 2-hop regressed to 31.9ms: 8x gather volume + uncoalesced 40-wide
// polling overwhelmed the coherent point). Two targeted changes vs R6:
//  (1) XCD colocation: the 8 cooperating WGs of each (L,dm) group now share
//      bid%8 (R6 had them round-robined across all 8 XCDs).
//  (2) Sentinel-gated staging: per-phase per-WG "done" sentinels; consumers poll
//      8 sentinels with 8 threads instead of 512 threads x 8-16 tagged values
//      hot-spinning against L3. Per-value tags + verify loops retained as the
//      correctness backstop, so the proven R6 protocol is unchanged; steady-state
//      chip-wide poll traffic drops ~60x. Theory: the ~4.8us/hop floor has a
//      large poll-storm congestion component at the coherent point.

typedef __attribute__((ext_vector_type(8))) short short8;
typedef __attribute__((ext_vector_type(4))) float floatx4;

#define MFMA16(a,b,c) __builtin_amdgcn_mfma_f32_16x16x32_bf16((a),(b),(c),0,0,0)

__device__ __forceinline__ short bf16_rne(float f) {
  uint32_t u = __float_as_uint(f);
  u += 0x7FFFu + ((u >> 16) & 1u);
  return (short)(u >> 16);
}
__device__ __forceinline__ float bf16f(short s) {
  return __uint_as_float(((uint32_t)(uint16_t)s) << 16);
}
__device__ __forceinline__ void st64(unsigned long long* p, unsigned long long v) {
  __hip_atomic_store(p, v, __ATOMIC_RELAXED, __HIP_MEMORY_SCOPE_AGENT);
}
__device__ __forceinline__ unsigned long long ld64(const unsigned long long* p) {
  return __hip_atomic_load(p, __ATOMIC_RELAXED, __HIP_MEMORY_SCOPE_AGENT);
}

#define SCALE_F 8388608.0f
#define INV_S   (1.0f/8388608.0f)

// ---- static device scratch ----
__device__ float g_X[50331648];            // X0: 32768 x 1536 (layer-0 x-projections)
__device__ short g_WTh[2][786432];         // per-layer x-proj weights, transposed, split hi
__device__ short g_WTl[2][786432];         // split lo
__device__ float g_biasL[2][1536];
__device__ unsigned long long g_ch[2][4][6][4096];  // per-layer scan channels
__device__ unsigned long long g_h0s[16777216];      // [t][row][col] tagged {tag, f32 h0f}
__device__ unsigned long long g_x1r[3145728];       // ring [t&31][row][1536] tagged {tag, f32}
__device__ unsigned long long g_sent[2][4][4][8];   // sentinels [L][dm][phase][cg]
__device__ unsigned g_epoch;

__global__ void bump_epoch() { g_epoch = g_epoch + 1u; }

// ------------------------------------------------------------------
__global__ void prep_x(const float* __restrict__ Wz1, const float* __restrict__ bz1,
                       const float* __restrict__ Wg1, const float* __restrict__ bg1,
                       const float* __restrict__ Wz2, const float* __restrict__ bz2,
                       const float* __restrict__ Wg2, const float* __restrict__ bg2,
                       int layer, int* __restrict__ d_out, int zero_extra) {
  int idx = blockIdx.x * 256 + threadIdx.x;   // grid covers 512*1536 exactly
  int k = idx / 1536;
  int c = idx - k * 1536;
  const float* W; const float* bb; int cc; int ncols;
  if (c < 512)       { W = Wz1; bb = bz1; cc = c;        ncols = 512; }
  else if (c < 768)  { W = Wg1; bb = bg1; cc = c - 512;  ncols = 256; }
  else if (c < 1280) { W = Wz2; bb = bz2; cc = c - 768;  ncols = 512; }
  else               { W = Wg2; bb = bg2; cc = c - 1280; ncols = 256; }
  float wv = W[(size_t)layer * 768 * ncols + (size_t)k * ncols + cc];
  short hi = bf16_rne(wv);
  short lo = bf16_rne(wv - bf16f(hi));
  g_WTh[layer][(size_t)c * 512 + k] = hi;
  g_WTl[layer][(size_t)c * 512 + k] = lo;
  if (k == 0) g_biasL[layer][c] = bb[layer * ncols + cc];
  if (zero_extra && idx < 6400) d_out[65536 + idx] = 0;   // saved[0] = h0 = zeros
}

// ------------------------------------------------------------------
__global__ __launch_bounds__(256)
void gemmx_kernel(const int* __restrict__ seq, const float* __restrict__ emb) {
  __shared__ float At[128][36];
  __shared__ short Bhi[128][40];
  __shared__ short Blo[128][40];
  __shared__ int toks[128];
  int tid = threadIdx.x;
  int r0 = blockIdx.x * 128;
  int c0 = blockIdx.y * 128;
  if (tid < 128) toks[tid] = seq[r0 + tid];
  int lane = tid & 63;
  int wid = tid >> 6;
  int wm = wid & 1, wn = wid >> 1;
  int lm = lane & 15, lq = lane >> 4;
  floatx4 zero4 = {0.f, 0.f, 0.f, 0.f};
  floatx4 acc[4][4];
#pragma unroll
  for (int a = 0; a < 4; ++a)
#pragma unroll
    for (int b = 0; b < 4; ++b) acc[a][b] = zero4;
  __syncthreads();
  int am = tid >> 1;
  int ah = (tid & 1) * 16;
  const float* arow = emb + (size_t)toks[am] * 512;
  const short* bh_base = g_WTh[0] + (size_t)(c0 + am) * 512;
  const short* bl_base = g_WTl[0] + (size_t)(c0 + am) * 512;
  for (int kb = 0; kb < 16; ++kb) {
    int k0 = kb * 32 + ah;
    float4 a0 = *(const float4*)(arow + k0);
    float4 a1 = *(const float4*)(arow + k0 + 4);
    float4 a2 = *(const float4*)(arow + k0 + 8);
    float4 a3 = *(const float4*)(arow + k0 + 12);
    short4 b0 = *(const short4*)(bh_base + k0);
    short4 b1 = *(const short4*)(bh_base + k0 + 4);
    short4 b2 = *(const short4*)(bh_base + k0 + 8);
    short4 b3 = *(const short4*)(bh_base + k0 + 12);
    short4 l0 = *(const short4*)(bl_base + k0);
    short4 l1 = *(const short4*)(bl_base + k0 + 4);
    short4 l2 = *(const short4*)(bl_base + k0 + 8);
    short4 l3 = *(const short4*)(bl_base + k0 + 12);
    __syncthreads();
    *(float4*)&At[am][ah]      = a0;
    *(float4*)&At[am][ah + 4]  = a1;
    *(float4*)&At[am][ah + 8]  = a2;
    *(float4*)&At[am][ah + 12] = a3;
    *(short4*)&Bhi[am][ah]      = b0;
    *(short4*)&Bhi[am][ah + 4]  = b1;
    *(short4*)&Bhi[am][ah + 8]  = b2;
    *(short4*)&Bhi[am][ah + 12] = b3;
    *(short4*)&Blo[am][ah]      = l0;
    *(short4*)&Blo[am][ah + 4]  = l1;
    *(short4*)&Blo[am][ah + 8]  = l2;
    *(short4*)&Blo[am][ah + 12] = l3;
    __syncthreads();
    short8 afh[4], afl[4];
#pragma unroll
    for (int mt = 0; mt < 4; ++mt) {
      const float* ap = &At[wm*64 + mt*16 + lm][lq*8];
#pragma unroll
      for (int j = 0; j < 8; ++j) {
        float v = ap[j];
        short hi = bf16_rne(v);
        afh[mt][j] = hi;
        afl[mt][j] = bf16_rne(v - bf16f(hi));
      }
    }
#pragma unroll
    for (int nt = 0; nt < 4; ++nt) {
      short8 bfh = *(short8*)&Bhi[wn*64 + nt*16 + lm][lq*8];
      short8 bfl = *(short8*)&Blo[wn*64 + nt*16 + lm][lq*8];
#pragma unroll
      for (int mt = 0; mt < 4; ++mt) {
        acc[mt][nt] = MFMA16(afh[mt], bfh, acc[mt][nt]);
        acc[mt][nt] = MFMA16(afl[mt], bfh, acc[mt][nt]);
        acc[mt][nt] = MFMA16(afh[mt], bfl, acc[mt][nt]);
      }
    }
  }
#pragma unroll
  for (int nt = 0; nt < 4; ++nt) {
    int gc = c0 + wn*64 + nt*16 + lm;
    float bv = g_biasL[0][gc];
#pragma unroll
    for (int mt = 0; mt < 4; ++mt) {
#pragma unroll
      for (int i = 0; i < 4; ++i) {
        int gr = r0 + wm*64 + mt*16 + lq*4 + i;
        g_X[(size_t)gr * 1536 + gc] = acc[mt][nt][i] + bv;
      }
    }
  }
}

// ------------------------------------------------------------------
__global__ __launch_bounds__(512, 2)
void fused_kernel(const float* __restrict__ Wz1g, const float* __restrict__ Wg1g,
                  const float* __restrict__ Wz2g, const float* __restrict__ Wg2g,
                  const int* __restrict__ lengths, int* __restrict__ d_out) {
  __shared__ int   h1i[16][260];
  __shared__ int   h2i[16][260];
  __shared__ short phi[16][264];
  __shared__ short pmi[16][264];
  __shared__ short plo[16][264];
  __shared__ float redbuf[2304];
  __shared__ int lens[16];
  __shared__ short ahs[16][520];
  __shared__ short als[16][520];

  int tid = threadIdx.x;
  int bid = blockIdx.x;
  int lane = tid & 63, wv = tid >> 6;   // 8 waves
  int lm = lane & 15, lq = lane >> 4;
  unsigned ep = g_epoch;

  if (bid >= 64) {
    // ================== role: X1 producer (48 WGs) ==================
    int xw = bid - 64;
    int r4 = xw & 3;        // row tile (16 rows) == dm of the L0 group it consumes
    int cs = xw >> 2;       // col slice (128 cols), 0..11
    int colx = cs * 128 + wv * 16 + lm;     // this lane's output column
    short8 bh[16], bl[16];
#pragma unroll
    for (int kf = 0; kf < 16; ++kf) {
      bh[kf] = *(const short8*)&g_WTh[1][(size_t)colx * 512 + kf * 32 + lq * 8];
      bl[kf] = *(const short8*)&g_WTl[1][(size_t)colx * 512 + kf * 32 + lq * 8];
    }
    float bvx = g_biasL[1][colx];
    int sr2 = tid >> 5;             // row 0..15
    int cb  = (tid & 31) * 16;      // 16 cols each

    for (int t = 0; t < 512; ++t) {
      unsigned tagt = (ep << 10) | (unsigned)(t + 1);
      // gate: wait until all 8 L0 WGs of domain r4 finished step t's P4
      if (tid < 8) {
        const unsigned long long* sp = &g_sent[0][r4][3][tid];
        while ((int)((unsigned)(ld64(sp) >> 32) - tagt) < 0) __builtin_amdgcn_s_sleep(2);
      }
      __syncthreads();
      // stage h0s[t] rows r4*16..+16 (one-shot after gate; verify loop = backstop)
      {
        const unsigned long long* hp = &g_h0s[((size_t)(t * 64) + r4 * 16 + sr2) * 512 + cb];
        unsigned long long v[16];
        do { v[0] = ld64(hp); } while ((unsigned)(v[0] >> 32) != tagt);
#pragma unroll
        for (int i = 1; i < 16; ++i) v[i] = ld64(hp + i);
        unsigned pend = 0;
#pragma unroll
        for (int i = 1; i < 16; ++i)
          if ((unsigned)(v[i] >> 32) != tagt) pend |= 1u << i;
        while (pend) {
          __builtin_amdgcn_s_sleep(1);
#pragma unroll
          for (int i = 1; i < 16; ++i)
            if (pend & (1u << i)) {
              v[i] = ld64(hp + i);
              if ((unsigned)(v[i] >> 32) == tagt) pend &= ~(1u << i);
            }
        }
#pragma unroll
        for (int i = 0; i < 16; ++i) {
          float f = __uint_as_float((unsigned)v[i]);
          short hi = bf16_rne(f);
          ahs[sr2][cb + i] = hi;
          als[sr2][cb + i] = bf16_rne(f - bf16f(hi));
        }
      }
      __syncthreads();
      floatx4 acc = {0.f, 0.f, 0.f, 0.f};
#pragma unroll
      for (int kf = 0; kf < 16; ++kf) {
        short8 a0 = *(short8*)&ahs[lm][kf * 32 + lq * 8];
        short8 a1 = *(short8*)&als[lm][kf * 32 + lq * 8];
        acc = MFMA16(a0, bh[kf], acc);
        acc = MFMA16(a1, bh[kf], acc);
        acc = MFMA16(a0, bl[kf], acc);
      }
      // throttle: don't clobber ring slots L1 hasn't consumed (window 24 of 32)
      if (t >= 25) {
        if (tid < 4) {
          unsigned need = (ep << 10) | (unsigned)(t - 24);
          while ((unsigned)(ld64(&g_ch[1][tid][5][0]) >> 32) < need) __builtin_amdgcn_s_sleep(2);
        }
      }
      __syncthreads();
#pragma unroll
      for (int i = 0; i < 4; ++i) {
        int row = r4 * 16 + lq * 4 + i;
        st64(&g_x1r[((size_t)(t & 31) * 64 + row) * 1536 + colx],
             ((unsigned long long)tagt << 32) | __float_as_uint(acc[i] + bvx));
      }
      __syncthreads();   // before next stage overwrites ahs/als
    }
    return;
  }

  // ================== role: scan (layer L), 32 WGs each ==================
  // XCD colocation: the 8 cooperating WGs of a (L,dm) group share bid%8.
  int grp = bid & 7;
  int cg  = bid >> 3;     // column group 0..7
  int L   = grp >> 2;
  int dm  = grp & 3;      // batch domain 0..3
  int rb0 = dm * 16;
  unsigned long long (*ch)[4096] = g_ch[L][dm];

  if (tid < 16) lens[tid] = lengths[rb0 + tid];
  for (int i = tid; i < 16 * 260; i += 512) { ((int*)h1i)[i] = 0; ((int*)h2i)[i] = 0; }

  // ---- preload recurrent-weight B-frags into registers (split-bf16) ----
  short8 wz1a[4], wz1b[4], wz1c[4], wz2a[4], wz2b[4], wz2c[4];
  short8 wg1a[2], wg1b[2], wg2a[2], wg2b[2];
  {
    int nt = wv & 3, kh = wv >> 2;
    int colz = cg * 64 + nt * 16 + lm;
    const float* W1 = Wz1g + (size_t)L * 768 * 512 + (size_t)512 * 512 + colz;
    const float* W2 = Wz2g + (size_t)L * 768 * 512 + (size_t)512 * 512 + colz;
#pragma unroll
    for (int ks = 0; ks < 4; ++ks) {
      int k0 = kh * 128 + ks * 32 + lq * 8;
      short8 t0, t1, t2, u0, u1, u2;
#pragma unroll
      for (int j = 0; j < 8; ++j) {
        float v = W1[(size_t)(k0 + j) * 512] * INV_S;   // pre-scale: A is raw int h
        short a0 = bf16_rne(v); float r1 = v - bf16f(a0);
        short a1 = bf16_rne(r1); float r2 = r1 - bf16f(a1);
        t0[j] = a0; t1[j] = a1; t2[j] = bf16_rne(r2);
        float v2 = W2[(size_t)(k0 + j) * 512] * INV_S;
        short d0 = bf16_rne(v2); float s1 = v2 - bf16f(d0);
        short d1 = bf16_rne(s1); float s2 = s1 - bf16f(d1);
        u0[j] = d0; u1[j] = d1; u2[j] = bf16_rne(s2);
      }
      wz1a[ks] = t0; wz1b[ks] = t1; wz1c[ks] = t2;
      wz2a[ks] = u0; wz2b[ks] = u1; wz2c[ks] = u2;
    }
    int ntg = wv & 1, kq = wv >> 1;
    int colg = cg * 32 + ntg * 16 + lm;
    const float* G1 = Wg1g + (size_t)L * 768 * 256 + (size_t)512 * 256 + colg;
    const float* G2 = Wg2g + (size_t)L * 768 * 256 + (size_t)512 * 256 + colg;
#pragma unroll
    for (int ks = 0; ks < 2; ++ks) {
      int k0 = kq * 64 + ks * 32 + lq * 8;
      short8 t0, t1, u0, u1;
#pragma unroll
      for (int j = 0; j < 8; ++j) {
        float v = G1[(size_t)(k0 + j) * 256];
        short a0 = bf16_rne(v);
        t0[j] = a0; t1[j] = bf16_rne(v - bf16f(a0));
        float v2 = G2[(size_t)(k0 + j) * 256];
        short d0 = bf16_rne(v2);
        u0[j] = d0; u1[j] = bf16_rne(v2 - bf16f(d0));
      }
      wg1a[ks] = t0; wg1b[ks] = t1; wg2a[ks] = u0; wg2b[ks] = u1;
    }
  }
  __syncthreads();

  int xr = tid & 15, xc = tid >> 4;   // xc 0..31
  int sr = tid >> 5, sc0 = (tid & 31) << 3;   // staging: 8 elems/thread

  auto ldx = [&](int tt, float& za, float& zb, float& g1x, float& ya, float& yb, float& g2x) {
    const float* base = g_X + (size_t)(tt * 64 + rb0 + xr) * 1536;
    float2 v1 = *(const float2*)(base + cg * 64 + 2 * xc);
    za = v1.x; zb = v1.y;
    g1x = base[512 + cg * 32 + xc];
    float2 v2 = *(const float2*)(base + 768 + cg * 64 + 2 * xc);
    ya = v2.x; yb = v2.y;
    g2x = base[1280 + cg * 32 + xc];
  };
  float cz1a = 0.f, cz1b = 0.f, cg1x = 0.f, cz2a = 0.f, cz2b = 0.f, cg2x = 0.f;
  if (L == 0) ldx(0, cz1a, cz1b, cg1x, cz2a, cz2b, cg2x);

#define GATE(PH, NEED)                                                         \
  {                                                                            \
    if (tid < 8) {                                                             \
      const unsigned long long* sp_ = &g_sent[L][dm][PH][tid];                 \
      while ((int)((unsigned)(ld64(sp_) >> 32) - (NEED)) < 0)                  \
        __builtin_amdgcn_s_sleep(2);                                           \
    }                                                                          \
    __syncthreads();                                                           \
  }

#define STAGE8(CHIDX, EXP, DEPOSIT)                                            \
  {                                                                            \
    const unsigned long long* cp_ = &ch[CHIDX][sr * 256 + sc0];                \
    unsigned long long v_[8];                                                  \
    do { v_[0] = ld64(cp_); } while ((unsigned)(v_[0] >> 32) != (EXP));        \
    _Pragma("unroll")                                                          \
    for (int i_ = 1; i_ < 8; ++i_) v_[i_] = ld64(cp_ + i_);                    \
    unsigned pend_ = 0;                                                        \
    _Pragma("unroll")                                                          \
    for (int i_ = 1; i_ < 8; ++i_)                                             \
      if ((unsigned)(v_[i_] >> 32) != (EXP)) pend_ |= 1u << i_;                \
    while (pend_) {                                                            \
      __builtin_amdgcn_s_sleep(1);                                             \
      _Pragma("unroll")                                                        \
      for (int i_ = 1; i_ < 8; ++i_)                                           \
        if (pend_ & (1u << i_)) {                                              \
          v_[i_] = ld64(cp_ + i_);                                             \
          if ((unsigned)(v_[i_] >> 32) == (EXP)) pend_ &= ~(1u << i_);         \
        }                                                                      \
    }                                                                          \
    _Pragma("unroll")                                                          \
    for (int i_ = 0; i_ < 8; ++i_) { DEPOSIT; }                                \
  }

#define SPLIT3(SRC)                                                            \
  {                                                                            \
    _Pragma("unroll")                                                          \
    for (int i_ = 0; i_ < 8; ++i_) {                                           \
      float v = (float)SRC[sr][sc0 + i_];                                      \
      short a0 = bf16_rne(v); float r1 = v - bf16f(a0);                        \
      short a1 = bf16_rne(r1); float r2 = r1 - bf16f(a1);                      \
      phi[sr][sc0 + i_] = a0; pmi[sr][sc0 + i_] = a1;                          \
      plo[sr][sc0 + i_] = bf16_rne(r2);                                       \
    }                                                                          \
  }

  for (int t = 0; t < 512; ++t) {
    unsigned tagp = (ep << 10) | (unsigned)(t + 1);
    auto rdx = [&](int col) -> float {     // just-in-time tagged X1 read (layer 1)
      const unsigned long long* p = &g_x1r[((size_t)(t & 31) * 64 + rb0 + xr) * 1536 + col];
      unsigned long long v;
      do { v = ld64(p); } while ((unsigned)(v >> 32) != tagp);
      return __uint_as_float((unsigned)v);
    };
    float nz1a, nz1b, ng1x, nz2a, nz2b, ng2x;
    if (L == 0) {
      int tn = (t + 1 < 512) ? t + 1 : t;
      ldx(tn, nz1a, nz1b, ng1x, nz2a, nz2b, ng2x);   // prefetch next step's X0
    }

    // ================= P1: z1 =================
    if (t > 0) {
      GATE(3, (ep << 10) | (unsigned)t);
      STAGE8(5, (ep << 10) | (unsigned)t, h2i[sr][sc0 + i_] = (int)(unsigned)v_[i_]);
    }
    SPLIT3(h2i);
    __syncthreads();
    {
      int nt = wv & 3, kh = wv >> 2;
      floatx4 acc = {0.f, 0.f, 0.f, 0.f};
#pragma unroll
      for (int ks = 0; ks < 4; ++ks) {
        int k0 = kh * 128 + ks * 32 + lq * 8;
        short8 a0 = *(short8*)&phi[lm][k0];
        short8 a1 = *(short8*)&pmi[lm][k0];
        short8 a2 = *(short8*)&plo[lm][k0];
        acc = MFMA16(a0, wz1a[ks], acc);
        acc = MFMA16(a0, wz1b[ks], acc);
        acc = MFMA16(a1, wz1a[ks], acc);
        acc = MFMA16(a1, wz1b[ks], acc);
        acc = MFMA16(a0, wz1c[ks], acc);
        acc = MFMA16(a2, wz1a[ks], acc);
      }
#pragma unroll
      for (int i = 0; i < 4; ++i) redbuf[kh * 1088 + (lq * 4 + i) * 68 + nt * 16 + lm] = acc[i];
    }
    __syncthreads();
    {
      if (L == 1) { cz1a = rdx(cg * 64 + 2 * xc); cz1b = rdx(cg * 64 + 2 * xc + 1); }
#pragma unroll
      for (int u = 0; u < 2; ++u) {
        int cc = 2 * xc + u;
        float pre = redbuf[xr * 68 + cc] + redbuf[1088 + xr * 68 + cc] + (u ? cz1b : cz1a);
        float s = 1.0f / (1.0f + expf(-pre));
        int gcol = cg * 64 + cc;
        if (gcol < 256) {
          float qf = floorf((0.875f * s + 0.125f) * 1024.0f);
          int qi = (int)qf; qi = qi < 1 ? 1 : (qi > 1024 ? 1024 : qi);
          st64(&ch[0][xr * 256 + gcol], ((unsigned long long)tagp << 32) | (unsigned)qi);
        } else {
          int rc = gcol - 256;
          float p = s * ((float)h2i[xr][rc] * INV_S);
          short p0 = bf16_rne(p);
          short p1s = bf16_rne(p - bf16f(p0));
          unsigned pay = ((unsigned)(unsigned short)p0 << 16) | (unsigned)(unsigned short)p1s;
          st64(&ch[1][xr * 256 + rc], ((unsigned long long)tagp << 32) | pay);
        }
      }
    }
    __syncthreads();   // drain P1 stores (compiler emits vmcnt(0) before barrier)
    if (tid == 0) st64(&g_sent[L][dm][0][cg], ((unsigned long long)tagp << 32) | 1u);
    GATE(0, tagp);

    // ================= P2: g1 + h1 update =================
    int qv;
    STAGE8(1, tagp, { unsigned pl_ = (unsigned)v_[i_];
                      phi[sr][sc0 + i_] = (short)(pl_ >> 16);
                      plo[sr][sc0 + i_] = (short)(pl_ & 0xFFFFu); });
    {
      const unsigned long long* qp = &ch[0][xr * 256 + cg * 32 + xc];
      unsigned long long q64;
      do { q64 = ld64(qp); } while ((unsigned)(q64 >> 32) != tagp);
      qv = (int)(unsigned)q64;
    }
    __syncthreads();
    {
      int ntg = wv & 1, kq = wv >> 1;
      floatx4 acc = {0.f, 0.f, 0.f, 0.f};
#pragma unroll
      for (int ks = 0; ks < 2; ++ks) {
        int k0 = kq * 64 + ks * 32 + lq * 8;
        short8 a0 = *(short8*)&phi[lm][k0];
        short8 a1 = *(short8*)&plo[lm][k0];
        acc = MFMA16(a0, wg1a[ks], acc);
        acc = MFMA16(a1, wg1a[ks], acc);
        acc = MFMA16(a0, wg1b[ks], acc);
      }
#pragma unroll
      for (int i = 0; i < 4; ++i) redbuf[kq * 576 + (lq * 4 + i) * 36 + ntg * 16 + lm] = acc[i];
    }
    __syncthreads();
    {
      if (L == 1) cg1x = rdx(512 + cg * 32 + xc);
      float pre = redbuf[xr * 36 + xc] + redbuf[576 + xr * 36 + xc]
                + redbuf[1152 + xr * 36 + xc] + redbuf[1728 + xr * 36 + xc] + cg1x;
      float g = tanhf(pre);
      int gc = cg * 32 + xc;
      int q = qv;
      int hold = h1i[xr][gc];
      float zf = (float)q * (1.0f / 1024.0f);
      int ni = (int)rintf((1.0f - zf) * g * SCALE_F);
      int hnew = (hold >> 10) * q + (((hold & 1023) * q) >> 10) + ni;
      if (t >= lens[xr]) hnew = hold;
      st64(&ch[2][xr * 256 + gc], ((unsigned long long)tagp << 32) | (unsigned)hnew);
      if (L == 0)
        st64(&g_h0s[((size_t)(t * 64) + rb0 + xr) * 512 + gc],
             ((unsigned long long)tagp << 32) | __float_as_uint((float)hnew * INV_S));
      else if (gc < 100) d_out[65536 + (t + 1) * 6400 + (rb0 + xr) * 100 + gc] = hnew;
      if (t == 511) d_out[L * 32768 + (rb0 + xr) * 512 + gc] = hnew;
    }
    __syncthreads();   // protect h1i old-value reads before P3 staging overwrites
    if (tid == 0) st64(&g_sent[L][dm][1][cg], ((unsigned long long)tagp << 32) | 1u);
    GATE(1, tagp);

    // ================= P3: z2 =================
    STAGE8(2, tagp, h1i[sr][sc0 + i_] = (int)(unsigned)v_[i_]);
    SPLIT3(h1i);
    __syncthreads();
    {
      int nt = wv & 3, kh = wv >> 2;
      floatx4 acc = {0.f, 0.f, 0.f, 0.f};
#pragma unroll
      for (int ks = 0; ks < 4; ++ks) {
        int k0 = kh * 128 + ks * 32 + lq * 8;
        short8 a0 = *(short8*)&phi[lm][k0];
        short8 a1 = *(short8*)&pmi[lm][k0];
        short8 a2 = *(short8*)&plo[lm][k0];
        acc = MFMA16(a0, wz2a[ks], acc);
        acc = MFMA16(a0, wz2b[ks], acc);
        acc = MFMA16(a1, wz2a[ks], acc);
        acc = MFMA16(a1, wz2b[ks], acc);
        acc = MFMA16(a0, wz2c[ks], acc);
        acc = MFMA16(a2, wz2a[ks], acc);
      }
#pragma unroll
      for (int i = 0; i < 4; ++i) redbuf[kh * 1088 + (lq * 4 + i) * 68 + nt * 16 + lm] = acc[i];
    }
    __syncthreads();
    {
      if (L == 1) { cz2a = rdx(768 + cg * 64 + 2 * xc); cz2b = rdx(768 + cg * 64 + 2 * xc + 1); }
#pragma unroll
      for (int u = 0; u < 2; ++u) {
        int cc = 2 * xc + u;
        float pre = redbuf[xr * 68 + cc] + redbuf[1088 + xr * 68 + cc] + (u ? cz2b : cz2a);
        float s = 1.0f / (1.0f + expf(-pre));
        int gcol = cg * 64 + cc;
        if (gcol < 256) {
          float qf = floorf((0.875f * s + 0.125f) * 1024.0f);
          int qi = (int)qf; qi = qi < 1 ? 1 : (qi > 1024 ? 1024 : qi);
          st64(&ch[3][xr * 256 + gcol], ((unsigned long long)tagp << 32) | (unsigned)qi);
        } else {
          int rc = gcol - 256;
          float p = s * ((float)h1i[xr][rc] * INV_S);
          short p0 = bf16_rne(p);
          short p1s = bf16_rne(p - bf16f(p0));
          unsigned pay = ((unsigned)(unsigned short)p0 << 16) | (unsigned)(unsigned short)p1s;
          st64(&ch[4][xr * 256 + rc], ((unsigned long long)tagp << 32) | pay);
        }
      }
    }
    __syncthreads();   // drain P3 stores
    if (tid == 0) st64(&g_sent[L][dm][2][cg], ((unsigned long long)tagp << 32) | 1u);
    GATE(2, tagp);

    // ================= P4: g2 + h2 update =================
    int qv2;
    STAGE8(4, tagp, { unsigned pl_ = (unsigned)v_[i_];
                      phi[sr][sc0 + i_] = (short)(pl_ >> 16);
                      plo[sr][sc0 + i_] = (short)(pl_ & 0xFFFFu); });
    {
      const unsigned long long* qp = &ch[3][xr * 256 + cg * 32 + xc];
      unsigned long long q64;
      do { q64 = ld64(qp); } while ((unsigned)(q64 >> 32) != tagp);
      qv2 = (int)(unsigned)q64;
    }
    __syncthreads();
    {
      int ntg = wv & 1, kq = wv >> 1;
      floatx4 acc = {0.f, 0.f, 0.f, 0.f};
#pragma unroll
      for (int ks = 0; ks < 2; ++ks) {
        int k0 = kq * 64 + ks * 32 + lq * 8;
        short8 a0 = *(short8*)&phi[lm][k0];
        short8 a1 = *(short8*)&plo[lm][k0];
        acc = MFMA16(a0, wg2a[ks], acc);
        acc = MFMA16(a1, wg2a[ks], acc);
        acc = MFMA16(a0, wg2b[ks], acc);
      }
#pragma unroll
      for (int i = 0; i < 4; ++i) redbuf[kq * 576 + (lq * 4 + i) * 36 + ntg * 16 + lm] = acc[i];
    }
    __syncthreads();
    {
      if (L == 1) cg2x = rdx(1280 + cg * 32 + xc);
      float pre = redbuf[xr * 36 + xc] + redbuf[576 + xr * 36 + xc]
                + redbuf[1152 + xr * 36 + xc] + redbuf[1728 + xr * 36 + xc] + cg2x;
      float g = tanhf(pre);
      int gc = cg * 32 + xc;
      int q = qv2;
      int hold = h2i[xr][gc];
      float zf = (float)q * (1.0f / 1024.0f);
      int ni = (int)rintf((1.0f - zf) * g * SCALE_F);
      int hnew = (hold >> 10) * q + (((hold & 1023) * q) >> 10) + ni;
      if (t >= lens[xr]) hnew = hold;
      st64(&ch[5][xr * 256 + gc], ((unsigned long long)tagp << 32) | (unsigned)hnew);
      if (L == 0)
        st64(&g_h0s[((size_t)(t * 64) + rb0 + xr) * 512 + 256 + gc],
             ((unsigned long long)tagp << 32) | __float_as_uint((float)hnew * INV_S));
      if (t == 511) d_out[L * 32768 + (rb0 + xr) * 512 + 256 + gc] = hnew;
    }
    __syncthreads();   // protect h2i old-value reads before next-step P1 staging
    if (tid == 0) st64(&g_sent[L][dm][3][cg], ((unsigned long long)tagp << 32) | 1u);

    if (L == 0) {
      cz1a = nz1a; cz1b = nz1b; cg1x = ng1x; cz2a = nz2a; cz2b = nz2b; cg2x = ng2x;
    }
  }
#undef GATE
#undef STAGE8
#undef SPLIT3
}

// ------------------------------------------------------------------
extern "C" void kernel_launch(void* const* d_in, const int* in_sizes, int n_in,
                              void* d_out, int out_size, void* d_ws, size_t ws_size,
                              hipStream_t stream) {
  const int*   seq     = (const int*)d_in[0];
  const int*   lengths = (const int*)d_in[1];
  const float* emb     = (const float*)d_in[2];
  const float* Wz1     = (const float*)d_in[3];
  const float* bz1     = (const float*)d_in[4];
  const float* Wg1     = (const float*)d_in[5];
  const float* bg1     = (const float*)d_in[6];
  const float* Wz2     = (const float*)d_in[7];
  const float* bz2     = (const float*)d_in[8];
  const float* Wg2     = (const float*)d_in[9];
  const float* bg2     = (const float*)d_in[10];
  int* out = (int*)d_out;
  (void)in_sizes; (void)n_in; (void)out_size; (void)d_ws; (void)ws_size;

  bump_epoch<<<1, 1, 0, stream>>>();
  prep_x<<<3072, 256, 0, stream>>>(Wz1, bz1, Wg1, bg1, Wz2, bz2, Wg2, bg2, 0, out, 1);
  prep_x<<<3072, 256, 0, stream>>>(Wz1, bz1, Wg1, bg1, Wz2, bz2, Wg2, bg2, 1, out, 0);
  gemmx_kernel<<<dim3(256, 12), 256, 0, stream>>>(seq, emb);
  fused_kernel<<<112, 512, 0, stream>>>(Wz1, Wg1, Wz2, Wg2, lengths, out);
}